// Round 1
// baseline (1452.298 us; speedup 1.0000x reference)
//
#include <hip/hip_runtime.h>
#include <math.h>

// Leapfrog on SPD(32) sector, eigh-free reformulation:
//   pi_half   = P - DT*sym(P S P)
//   V         = 2*DT * S pi_half S
//   Sigma_new = sym( exp(V S^{-1}) S ) + 1e-8 I      (== S^{1/2} exp(S^{-1/2}V S^{-1/2}) S^{1/2})
//   S^{-1} via Newton-Schulz (self-correcting), exp via scaling-and-squaring Taylor-8.
// phi_new = retract_mod2pi(phi + DT*pi_phi), done in double (branch at theta mod 2pi == pi
// is discontinuous; double matches the float64 numpy reference's branch choice).

#define KDIM 32
#define LD   36        // LDS row stride in floats: 144B rows keep float4 alignment,
                       // and (36 mod 32)=4 spreads wave's 8 A-row reads over disjoint bank quads
#define DTf  0.01f

__device__ __forceinline__ void mm32(const float* A, const float* B, float* C,
                                     int row, int col0, float scale,
                                     const float* D, float beta, float diag)
{
    // C[row][col0..col0+3] = scale * (A·B)[row][col0..+3] + beta*D[...] + diag*I
    float a0 = 0.f, a1 = 0.f, a2 = 0.f, a3 = 0.f;
    const float* Ar = A + row * LD;
    const float* Bc = B + col0;
#pragma unroll
    for (int k = 0; k < KDIM; k += 4) {
        const float4 av = *(const float4*)(Ar + k);
        const float4 b0 = *(const float4*)(Bc + (k + 0) * LD);
        const float4 b1 = *(const float4*)(Bc + (k + 1) * LD);
        const float4 b2 = *(const float4*)(Bc + (k + 2) * LD);
        const float4 b3 = *(const float4*)(Bc + (k + 3) * LD);
        a0 = fmaf(av.x, b0.x, a0); a1 = fmaf(av.x, b0.y, a1); a2 = fmaf(av.x, b0.z, a2); a3 = fmaf(av.x, b0.w, a3);
        a0 = fmaf(av.y, b1.x, a0); a1 = fmaf(av.y, b1.y, a1); a2 = fmaf(av.y, b1.z, a2); a3 = fmaf(av.y, b1.w, a3);
        a0 = fmaf(av.z, b2.x, a0); a1 = fmaf(av.z, b2.y, a1); a2 = fmaf(av.z, b2.z, a2); a3 = fmaf(av.z, b2.w, a3);
        a0 = fmaf(av.w, b3.x, a0); a1 = fmaf(av.w, b3.y, a1); a2 = fmaf(av.w, b3.z, a2); a3 = fmaf(av.w, b3.w, a3);
    }
    float4 r;
    r.x = scale * a0; r.y = scale * a1; r.z = scale * a2; r.w = scale * a3;
    if (D != nullptr) {
        const float4 d = *(const float4*)(D + row * LD + col0);
        r.x = fmaf(beta, d.x, r.x); r.y = fmaf(beta, d.y, r.y);
        r.z = fmaf(beta, d.z, r.z); r.w = fmaf(beta, d.w, r.w);
    }
    if (diag != 0.f) {
        if (row == col0 + 0) r.x += diag;
        if (row == col0 + 1) r.y += diag;
        if (row == col0 + 2) r.z += diag;
        if (row == col0 + 3) r.w += diag;
    }
    *(float4*)(C + row * LD + col0) = r;
}

__global__ __launch_bounds__(256)
void leapfrog_mat(const float* __restrict__ Sg, const float* __restrict__ Pg,
                  float* __restrict__ out)
{
    __shared__ __align__(16) float sS[KDIM * LD];
    __shared__ __align__(16) float sP[KDIM * LD];
    __shared__ __align__(16) float sT[KDIM * LD];
    __shared__ __align__(16) float sV[KDIM * LD];
    __shared__ __align__(16) float sX0[KDIM * LD];
    __shared__ __align__(16) float sX1[KDIM * LD];
    __shared__ float red[32];
    __shared__ float sScal[2];
    __shared__ int   sInt[1];

    const int bn   = blockIdx.x;
    const int tid  = threadIdx.x;
    const int row  = tid >> 3;
    const int col0 = (tid & 7) * 4;

    // ---- load Sigma, pi_Sigma (coalesced float4) ----
    {
        const float4 s4 = *(const float4*)(Sg + (size_t)bn * 1024 + tid * 4);
        const float4 p4 = *(const float4*)(Pg + (size_t)bn * 1024 + tid * 4);
        *(float4*)(sS + row * LD + col0) = s4;
        *(float4*)(sP + row * LD + col0) = p4;
    }
    __syncthreads();

    // ---- c = max row abs-sum of S (>= lambda_max); X0 = I/c ----
    if (tid < 32) {
        float s = 0.f;
        for (int k = 0; k < KDIM; ++k) s += fabsf(sS[tid * LD + k]);
        red[tid] = s;
    }
    __syncthreads();
    if (tid == 0) {
        float m = red[0];
        for (int i = 1; i < 32; ++i) m = fmaxf(m, red[i]);
        sScal[0] = 1.0f / m;
    }
    __syncthreads();

    // ---- T = P S ;  V = T P = P S P ----
    mm32(sP, sS, sT, row, col0, 1.f, nullptr, 0.f, 0.f);
    __syncthreads();
    mm32(sT, sP, sV, row, col0, 1.f, nullptr, 0.f, 0.f);
    __syncthreads();

    // ---- P <- pi_half = P - DT*0.5*(V + V^T) ----
    {
        float4 v = *(const float4*)(sV + row * LD + col0);
        const float vt0 = sV[(col0 + 0) * LD + row];
        const float vt1 = sV[(col0 + 1) * LD + row];
        const float vt2 = sV[(col0 + 2) * LD + row];
        const float vt3 = sV[(col0 + 3) * LD + row];
        float4 p = *(const float4*)(sP + row * LD + col0);
        p.x -= DTf * 0.5f * (v.x + vt0);
        p.y -= DTf * 0.5f * (v.y + vt1);
        p.z -= DTf * 0.5f * (v.z + vt2);
        p.w -= DTf * 0.5f * (v.w + vt3);
        *(float4*)(sP + row * LD + col0) = p;
    }
    __syncthreads();

    // ---- T = S*pi_half ; V = 2*DT*(T*S) ----
    mm32(sS, sP, sT, row, col0, 1.f, nullptr, 0.f, 0.f);
    __syncthreads();
    mm32(sT, sS, sV, row, col0, 2.0f * DTf, nullptr, 0.f, 0.f);
    __syncthreads();

    // ---- Newton-Schulz inverse: X <- X(2I - S X), 10 iters ----
    {
        const float invc = sScal[0];
        float4 x;
        x.x = (row == col0 + 0) ? invc : 0.f;
        x.y = (row == col0 + 1) ? invc : 0.f;
        x.z = (row == col0 + 2) ? invc : 0.f;
        x.w = (row == col0 + 3) ? invc : 0.f;
        *(float4*)(sX0 + row * LD + col0) = x;
    }
    __syncthreads();
    float* Xc = sX0;
    float* Xn = sX1;
    for (int it = 0; it < 10; ++it) {
        mm32(sS, Xc, sT, row, col0, 1.f, nullptr, 0.f, 0.f);   // T = S X
        __syncthreads();
        mm32(Xc, sT, Xn, row, col0, -1.f, Xc, 2.f, 0.f);       // Xn = 2X - X(SX)
        __syncthreads();
        float* tmp = Xc; Xc = Xn; Xn = tmp;
    }

    // ---- M = V * S^{-1}  (into sP; pi_half no longer needed) ----
    mm32(sV, Xc, sP, row, col0, 1.f, nullptr, 0.f, 0.f);
    __syncthreads();

    // ---- scaling: s = ceil(log2(||M||_F / 0.25)), M *= 2^-s ----
    if (tid < 32) {
        float s = 0.f;
        for (int k = 0; k < KDIM; ++k) { const float v = sP[tid * LD + k]; s = fmaf(v, v, s); }
        red[tid] = s;
    }
    __syncthreads();
    if (tid == 0) {
        float s = 0.f;
        for (int i = 0; i < 32; ++i) s += red[i];
        float f = sqrtf(s);
        int sh = 0;
        while (f > 0.25f && sh < 12) { f *= 0.5f; ++sh; }
        sInt[0]  = sh;
        sScal[1] = ldexpf(1.f, -sh);
    }
    __syncthreads();
    const int sh = sInt[0];
    {
        const float sc = sScal[1];
        float4 m = *(const float4*)(sP + row * LD + col0);
        m.x *= sc; m.y *= sc; m.z *= sc; m.w *= sc;
        *(float4*)(sP + row * LD + col0) = m;
    }
    __syncthreads();

    // ---- exp(Ms): Horner Taylor order 8:  R = I + Ms/8; R = I + Ms*R/d, d=7..1 ----
    {
        float4 m = *(const float4*)(sP + row * LD + col0);
        float4 r;
        r.x = 0.125f * m.x + ((row == col0 + 0) ? 1.f : 0.f);
        r.y = 0.125f * m.y + ((row == col0 + 1) ? 1.f : 0.f);
        r.z = 0.125f * m.z + ((row == col0 + 2) ? 1.f : 0.f);
        r.w = 0.125f * m.w + ((row == col0 + 3) ? 1.f : 0.f);
        *(float4*)(sX0 + row * LD + col0) = r;
    }
    __syncthreads();
    Xc = sX0; Xn = sX1;
    for (int d = 7; d >= 1; --d) {
        mm32(sP, Xc, Xn, row, col0, 1.0f / (float)d, nullptr, 0.f, 1.0f);
        __syncthreads();
        float* tmp = Xc; Xc = Xn; Xn = tmp;
    }
    // ---- undo scaling: square s times ----
    for (int i = 0; i < sh; ++i) {
        mm32(Xc, Xc, Xn, row, col0, 1.f, nullptr, 0.f, 0.f);
        __syncthreads();
        float* tmp = Xc; Xc = Xn; Xn = tmp;
    }

    // ---- Sigma_new = sym(R * S) + 1e-8 I ; write out ----
    mm32(Xc, sS, sT, row, col0, 1.f, nullptr, 0.f, 0.f);
    __syncthreads();
    {
        const size_t base = (size_t)bn * 1027;
#pragma unroll
        for (int j = 0; j < 4; ++j) {
            const int c = col0 + j;
            float v = 0.5f * (sT[row * LD + c] + sT[c * LD + row]);
            if (row == c) v += 1e-8f;
            out[base + row * 32 + c] = v;
        }
    }
}

__global__ __launch_bounds__(256)
void leapfrog_phi(const float* __restrict__ phi, const float* __restrict__ piphi,
                  float* __restrict__ out, int total)
{
    const int i = blockIdx.x * blockDim.x + threadIdx.x;
    if (i >= total) return;
    const double TWO_PI = 6.283185307179586476925287;
    const double PI_    = 3.141592653589793238462643;
    const double x = (double)phi[3 * i + 0] + 0.01 * (double)piphi[3 * i + 0];
    const double y = (double)phi[3 * i + 1] + 0.01 * (double)piphi[3 * i + 1];
    const double z = (double)phi[3 * i + 2] + 0.01 * (double)piphi[3 * i + 2];
    const double theta = sqrt(x * x + y * y + z * z);
    const double ts = theta > 1e-12 ? theta : 1e-12;
    const double ax = x / ts, ay = y / ts, az = z / ts;
    const double tw = fmod(theta, TWO_PI);
    double t, sgn;
    if (tw > PI_) { t = TWO_PI - tw; sgn = -1.0; }
    else          { t = tw;          sgn = 1.0;  }
    const double rmax = PI_ - 0.01;
    if (t > rmax) t = rmax;
    const double f = sgn * t;
    const size_t base = (size_t)i * 1027 + 1024;
    out[base + 0] = (float)(ax * f);
    out[base + 1] = (float)(ay * f);
    out[base + 2] = (float)(az * f);
}

extern "C" void kernel_launch(void* const* d_in, const int* in_sizes, int n_in,
                              void* d_out, int out_size, void* d_ws, size_t ws_size,
                              hipStream_t stream)
{
    const float* Sg     = (const float*)d_in[0];
    const float* Pg     = (const float*)d_in[1];
    const float* phig   = (const float*)d_in[2];
    const float* piphig = (const float*)d_in[3];
    float* out = (float*)d_out;

    const int total = in_sizes[0] / 1024;   // B*N = 32768 matrices

    leapfrog_mat<<<total, 256, 0, stream>>>(Sg, Pg, out);
    leapfrog_phi<<<(total + 255) / 256, 256, 0, stream>>>(phig, piphig, out, total);
}

// Round 2
// 533.684 us; speedup vs baseline: 2.7213x; 2.7213x over previous
//
#include <hip/hip_runtime.h>
#include <math.h>

// Leapfrog on SPD(32) sector, eigh-free AND inverse-free reformulation:
//   pi_half   = P - DT*sym(P S P)
//   Sigma_new = sym( exp(2*DT * S * pi_half) * S ) + 1e-8 I
// since  exp_Sigma(V) = S^{1/2} exp(S^{-1/2} V S^{-1/2}) S^{1/2} = exp(V S^{-1}) S
// and    V S^{-1} = DT * 2 S pi_half S S^{-1} = 2 DT S pi_half.
// exp via scaling-and-squaring + order-8 Taylor (Horner); scale folded into mm scales.
// phi_new = retract_mod2pi(phi + DT*pi_phi) in double (discontinuous branch at theta
// mod 2pi == pi must match the float64 numpy reference).

#define KDIM 32
#define LD   36        // LDS row stride in floats: 144B rows keep float4 alignment,
                       // and (36 mod 32)=4 spreads wave's 8 A-row reads over disjoint bank quads
#define DTf  0.01f

__device__ __forceinline__ void mm32(const float* A, const float* B, float* C,
                                     int row, int col0, float scale, float diag)
{
    // C[row][col0..col0+3] = scale * (A.B)[row][col0..+3] + diag*I
    float a0 = 0.f, a1 = 0.f, a2 = 0.f, a3 = 0.f;
    const float* Ar = A + row * LD;
    const float* Bc = B + col0;
#pragma unroll
    for (int k = 0; k < KDIM; k += 4) {
        const float4 av = *(const float4*)(Ar + k);
        const float4 b0 = *(const float4*)(Bc + (k + 0) * LD);
        const float4 b1 = *(const float4*)(Bc + (k + 1) * LD);
        const float4 b2 = *(const float4*)(Bc + (k + 2) * LD);
        const float4 b3 = *(const float4*)(Bc + (k + 3) * LD);
        a0 = fmaf(av.x, b0.x, a0); a1 = fmaf(av.x, b0.y, a1); a2 = fmaf(av.x, b0.z, a2); a3 = fmaf(av.x, b0.w, a3);
        a0 = fmaf(av.y, b1.x, a0); a1 = fmaf(av.y, b1.y, a1); a2 = fmaf(av.y, b1.z, a2); a3 = fmaf(av.y, b1.w, a3);
        a0 = fmaf(av.z, b2.x, a0); a1 = fmaf(av.z, b2.y, a1); a2 = fmaf(av.z, b2.z, a2); a3 = fmaf(av.z, b2.w, a3);
        a0 = fmaf(av.w, b3.x, a0); a1 = fmaf(av.w, b3.y, a1); a2 = fmaf(av.w, b3.z, a2); a3 = fmaf(av.w, b3.w, a3);
    }
    float4 r;
    r.x = scale * a0; r.y = scale * a1; r.z = scale * a2; r.w = scale * a3;
    if (diag != 0.f) {
        if (row == col0 + 0) r.x += diag;
        if (row == col0 + 1) r.y += diag;
        if (row == col0 + 2) r.z += diag;
        if (row == col0 + 3) r.w += diag;
    }
    *(float4*)(C + row * LD + col0) = r;
}

__global__ __launch_bounds__(256)
void leapfrog_mat(const float* __restrict__ Sg, const float* __restrict__ Pg,
                  float* __restrict__ out)
{
    __shared__ __align__(16) float sS[KDIM * LD];
    __shared__ __align__(16) float sP[KDIM * LD];
    __shared__ __align__(16) float sM[KDIM * LD];
    __shared__ __align__(16) float sX0[KDIM * LD];
    __shared__ __align__(16) float sX1[KDIM * LD];
    __shared__ float red[4];
    __shared__ float sScal[1];
    __shared__ int   sInt[1];

    const int bn   = blockIdx.x;
    const int tid  = threadIdx.x;
    const int row  = tid >> 3;
    const int col0 = (tid & 7) * 4;

    // ---- load Sigma, pi_Sigma (coalesced float4) ----
    {
        const float4 s4 = *(const float4*)(Sg + (size_t)bn * 1024 + tid * 4);
        const float4 p4 = *(const float4*)(Pg + (size_t)bn * 1024 + tid * 4);
        *(float4*)(sS + row * LD + col0) = s4;
        *(float4*)(sP + row * LD + col0) = p4;
    }
    __syncthreads();

    // ---- T = P S (sX1);  V = T P = P S P (sX0) ----
    mm32(sP, sS, sX1, row, col0, 1.f, 0.f);
    __syncthreads();
    mm32(sX1, sP, sX0, row, col0, 1.f, 0.f);
    __syncthreads();

    // ---- P <- pi_half = P - DT*0.5*(V + V^T) ----
    {
        float4 v = *(const float4*)(sX0 + row * LD + col0);
        const float vt0 = sX0[(col0 + 0) * LD + row];
        const float vt1 = sX0[(col0 + 1) * LD + row];
        const float vt2 = sX0[(col0 + 2) * LD + row];
        const float vt3 = sX0[(col0 + 3) * LD + row];
        float4 p = *(const float4*)(sP + row * LD + col0);
        p.x -= DTf * 0.5f * (v.x + vt0);
        p.y -= DTf * 0.5f * (v.y + vt1);
        p.z -= DTf * 0.5f * (v.z + vt2);
        p.w -= DTf * 0.5f * (v.w + vt3);
        *(float4*)(sP + row * LD + col0) = p;
    }
    __syncthreads();

    // ---- M = 2*DT * S * pi_half   (== V S^{-1} of the expmap, inverse-free) ----
    mm32(sS, sP, sM, row, col0, 2.0f * DTf, 0.f);
    __syncthreads();

    // ---- ||M||_F^2 via wave-shuffle reduce ----
    {
        const float4 m = *(const float4*)(sM + row * LD + col0);
        float part = m.x * m.x + m.y * m.y + m.z * m.z + m.w * m.w;
        for (int off = 32; off > 0; off >>= 1) part += __shfl_down(part, off, 64);
        if ((tid & 63) == 0) red[tid >> 6] = part;
    }
    __syncthreads();
    if (tid == 0) {
        const float f2 = red[0] + red[1] + red[2] + red[3];
        const float f  = sqrtf(f2);
        int e;
        frexpf(f, &e);                 // f = m * 2^e, m in [0.5,1)
        int sh = e + 1;                // ||M|| * 2^-sh in [0.25, 0.5)
        if (sh < 0) sh = 0;
        if (sh > 14) sh = 14;
        sInt[0]  = sh;
        sScal[0] = ldexpf(1.f, -sh);
    }
    __syncthreads();
    const int   sh = sInt[0];
    const float sc = sScal[0];

    // ---- exp(M*sc) by Horner Taylor-8: R = I + (sc/8)M; R = I + (sc/d) M R, d=7..1 ----
    {
        const float4 m = *(const float4*)(sM + row * LD + col0);
        float4 r;
        const float c8 = sc * 0.125f;
        r.x = c8 * m.x + ((row == col0 + 0) ? 1.f : 0.f);
        r.y = c8 * m.y + ((row == col0 + 1) ? 1.f : 0.f);
        r.z = c8 * m.z + ((row == col0 + 2) ? 1.f : 0.f);
        r.w = c8 * m.w + ((row == col0 + 3) ? 1.f : 0.f);
        *(float4*)(sX0 + row * LD + col0) = r;
    }
    __syncthreads();
    float* Xc = sX0;
    float* Xn = sX1;
#pragma unroll
    for (int d = 7; d >= 1; --d) {
        mm32(sM, Xc, Xn, row, col0, sc / (float)d, 1.0f);
        __syncthreads();
        float* tmp = Xc; Xc = Xn; Xn = tmp;
    }
    // ---- undo scaling: square sh times ----
    for (int i = 0; i < sh; ++i) {
        mm32(Xc, Xc, Xn, row, col0, 1.f, 0.f);
        __syncthreads();
        float* tmp = Xc; Xc = Xn; Xn = tmp;
    }

    // ---- Sigma_new = sym(R * S) + 1e-8 I ; write out ----
    mm32(Xc, sS, Xn, row, col0, 1.f, 0.f);
    __syncthreads();
    {
        const size_t base = (size_t)bn * 1027;
#pragma unroll
        for (int j = 0; j < 4; ++j) {
            const int c = col0 + j;
            float v = 0.5f * (Xn[row * LD + c] + Xn[c * LD + row]);
            if (row == c) v += 1e-8f;
            out[base + row * 32 + c] = v;
        }
    }
}

__global__ __launch_bounds__(256)
void leapfrog_phi(const float* __restrict__ phi, const float* __restrict__ piphi,
                  float* __restrict__ out, int total)
{
    const int i = blockIdx.x * blockDim.x + threadIdx.x;
    if (i >= total) return;
    const double TWO_PI = 6.283185307179586476925287;
    const double PI_    = 3.141592653589793238462643;
    const double x = (double)phi[3 * i + 0] + 0.01 * (double)piphi[3 * i + 0];
    const double y = (double)phi[3 * i + 1] + 0.01 * (double)piphi[3 * i + 1];
    const double z = (double)phi[3 * i + 2] + 0.01 * (double)piphi[3 * i + 2];
    const double theta = sqrt(x * x + y * y + z * z);
    const double ts = theta > 1e-12 ? theta : 1e-12;
    const double ax = x / ts, ay = y / ts, az = z / ts;
    const double tw = fmod(theta, TWO_PI);
    double t, sgn;
    if (tw > PI_) { t = TWO_PI - tw; sgn = -1.0; }
    else          { t = tw;          sgn = 1.0;  }
    const double rmax = PI_ - 0.01;
    if (t > rmax) t = rmax;
    const double f = sgn * t;
    const size_t base = (size_t)i * 1027 + 1024;
    out[base + 0] = (float)(ax * f);
    out[base + 1] = (float)(ay * f);
    out[base + 2] = (float)(az * f);
}

extern "C" void kernel_launch(void* const* d_in, const int* in_sizes, int n_in,
                              void* d_out, int out_size, void* d_ws, size_t ws_size,
                              hipStream_t stream)
{
    const float* Sg     = (const float*)d_in[0];
    const float* Pg     = (const float*)d_in[1];
    const float* phig   = (const float*)d_in[2];
    const float* piphig = (const float*)d_in[3];
    float* out = (float*)d_out;

    const int total = in_sizes[0] / 1024;   // B*N = 32768 matrices

    leapfrog_mat<<<total, 256, 0, stream>>>(Sg, Pg, out);
    leapfrog_phi<<<(total + 255) / 256, 256, 0, stream>>>(phig, piphig, out, total);
}

// Round 3
// 96.265 us; speedup vs baseline: 15.0864x; 5.5439x over previous
//
#include <hip/hip_runtime.h>
#include <hip/hip_bf16.h>
#include <math.h>

// Leapfrog on SPD(32), eigh-free, inverse-free, barrier-free MFMA version.
//   U = S·P ; G = P·U (= PSP, symmetric) ; pi_half = P - DT·G
//   M = 2DT·S·pi_half = 0.02·U - 2e-4·H,  H = S·G
//   Sigma_new = sym(exp(M)·S) + 1e-8·I = sym(S·exp(M^T)) + 1e-8·I
// One wave per matrix; 32x32x16 bf16 MFMA; D-layout results converted to
// B-fragments via lane-pair (c, c+32) __shfl_xor exchange. ||M|| < ~0.15 so
// plain Taylor-7 (no scaling/squaring). Final S·E uses hi/lo split bf16.

typedef unsigned int u32;
typedef __attribute__((ext_vector_type(8))) short bf16x8;
typedef __attribute__((ext_vector_type(16))) float f32x16;

#define NPAD 40   // bf16 elements per staged row (80 B, odd multiple of 16 B)
#define FPAD 36   // f32 elements per row of sym buffer

union U4 { u32 u[4]; bf16x8 v; };

__device__ __forceinline__ bf16x8 mk8(u32 a, u32 b, u32 c, u32 d) {
    U4 t; t.u[0] = a; t.u[1] = b; t.u[2] = c; t.u[3] = d; return t.v;
}

__device__ __forceinline__ u32 pk2(float x, float y) {
    float2 f2; f2.x = x; f2.y = y;
    __hip_bfloat162 h2 = __float22bfloat162_rn(f2);
    union { __hip_bfloat162 h; u32 u; } c; c.h = h2; return c.u;
}

__device__ __forceinline__ float asfloat(u32 b) {
    union { u32 u; float f; } c; c.u = b; return c.f;
}

struct Frag8 { u32 r[8]; };

// exchange packed-pair regs p[8] (D-layout pairs) into B-fragment order
__device__ __forceinline__ void xchg(const u32* p, int h, Frag8& B) {
    u32 s0 = h ? p[0] : p[2];
    u32 s1 = h ? p[1] : p[3];
    u32 r0 = __shfl_xor(s0, 32, 64);
    u32 r1 = __shfl_xor(s1, 32, 64);
    B.r[0] = h ? r0 : p[0];
    B.r[1] = h ? r1 : p[1];
    B.r[2] = h ? p[2] : r0;
    B.r[3] = h ? p[3] : r1;
    u32 s2 = h ? p[4] : p[6];
    u32 s3 = h ? p[5] : p[7];
    u32 r2 = __shfl_xor(s2, 32, 64);
    u32 r3 = __shfl_xor(s3, 32, 64);
    B.r[4] = h ? r2 : p[4];
    B.r[5] = h ? r3 : p[5];
    B.r[6] = h ? p[6] : r2;
    B.r[7] = h ? p[7] : r3;
}

// D-layout f32x16 -> bf16 B-fragment (optionally pre-scaled)
__device__ __forceinline__ void bconv(const f32x16& X, int h, float scale, Frag8& B) {
    u32 p[8];
#pragma unroll
    for (int i = 0; i < 8; ++i) p[i] = pk2(X[2*i] * scale, X[2*i+1] * scale);
    xchg(p, h, B);
}

// D-layout f32x16 -> hi and lo bf16 B-fragments (error-compensated split)
__device__ __forceinline__ void bconv_split(const f32x16& X, int h, Frag8& Bh, Frag8& Bl) {
    u32 p[8], q[8];
#pragma unroll
    for (int i = 0; i < 8; ++i) {
        p[i] = pk2(X[2*i], X[2*i+1]);
        const float hx = asfloat(p[i] << 16);
        const float hy = asfloat(p[i] & 0xffff0000u);
        q[i] = pk2(X[2*i] - hx, X[2*i+1] - hy);
    }
    xchg(p, h, Bh);
    xchg(q, h, Bl);
}

__device__ __forceinline__ f32x16 MFMA1(const u32* a, const u32* b, f32x16 acc) {
    return __builtin_amdgcn_mfma_f32_32x32x16_bf16(
        mk8(a[0], a[1], a[2], a[3]), mk8(b[0], b[1], b[2], b[3]), acc, 0, 0, 0);
}

__device__ __forceinline__ f32x16 matmul(const Frag8& A, const Frag8& B, f32x16 acc) {
    acc = MFMA1(A.r,     B.r,     acc);   // k = 0..15
    acc = MFMA1(A.r + 4, B.r + 4, acc);   // k = 16..31
    return acc;
}

__global__ __launch_bounds__(256)
void leapfrog_mat(const float* __restrict__ Sg, const float* __restrict__ Pg,
                  float* __restrict__ out, int total)
{
    __shared__ __align__(16) char lds[4 * 7680];

    const int w  = threadIdx.x >> 6;
    const int l  = threadIdx.x & 63;
    const int bn = blockIdx.x * 4 + w;
    if (bn >= total) return;            // wave-uniform, no barriers in kernel

    char* my = lds + w * 7680;
    unsigned short* sh = (unsigned short*)(my);          // S hi  [32][40] bf16
    unsigned short* sl = (unsigned short*)(my + 2560);   // S lo
    unsigned short* ph = (unsigned short*)(my + 5120);   // P hi
    float*          sy = (float*)(my);                   // sym f32 [32][36] (reuse)

    const size_t gbase = (size_t)bn * 1024;

    // ---- stage S (hi+lo) and P (hi) into LDS as row-major bf16 ----
#pragma unroll
    for (int rnd = 0; rnd < 4; ++rnd) {
        const int idx = rnd * 256 + l * 4;
        const int row = idx >> 5, col = idx & 31;
        const float4 s4 = *(const float4*)(Sg + gbase + idx);
        const float4 p4 = *(const float4*)(Pg + gbase + idx);
        const u32 h0 = pk2(s4.x, s4.y), h1 = pk2(s4.z, s4.w);
        const float lx = s4.x - asfloat(h0 << 16);
        const float ly = s4.y - asfloat(h0 & 0xffff0000u);
        const float lz = s4.z - asfloat(h1 << 16);
        const float lw = s4.w - asfloat(h1 & 0xffff0000u);
        const u32 l0 = pk2(lx, ly), l1 = pk2(lz, lw);
        const u32 q0 = pk2(p4.x, p4.y), q1 = pk2(p4.z, p4.w);
        uint2 t;
        t.x = h0; t.y = h1; *(uint2*)(sh + row * NPAD + col) = t;
        t.x = l0; t.y = l1; *(uint2*)(sl + row * NPAD + col) = t;
        t.x = q0; t.y = q1; *(uint2*)(ph + row * NPAD + col) = t;
    }

    // ---- A-fragments (row l&31, cols h*8.. / 16+h*8..); S,P symmetric so
    //      the same registers serve as B-fragments where needed ----
    const int fr = l & 31;
    const int h  = l >> 5;
    Frag8 FS, FP;
    {
        const uint4 a0 = *(const uint4*)(sh + fr * NPAD + h * 8);
        const uint4 a1 = *(const uint4*)(sh + fr * NPAD + 16 + h * 8);
        FS.r[0]=a0.x; FS.r[1]=a0.y; FS.r[2]=a0.z; FS.r[3]=a0.w;
        FS.r[4]=a1.x; FS.r[5]=a1.y; FS.r[6]=a1.z; FS.r[7]=a1.w;
        const uint4 b0 = *(const uint4*)(ph + fr * NPAD + h * 8);
        const uint4 b1 = *(const uint4*)(ph + fr * NPAD + 16 + h * 8);
        FP.r[0]=b0.x; FP.r[1]=b0.y; FP.r[2]=b0.z; FP.r[3]=b0.w;
        FP.r[4]=b1.x; FP.r[5]=b1.y; FP.r[6]=b1.z; FP.r[7]=b1.w;
    }

    f32x16 Z0;
#pragma unroll
    for (int i = 0; i < 16; ++i) Z0[i] = 0.f;

    // identity in D-layout: row (i&3)+8*(i>>2)+4h, col fr
    f32x16 If;
#pragma unroll
    for (int i = 0; i < 16; ++i)
        If[i] = (((i & 3) + 8 * (i >> 2) + 4 * h) == fr) ? 1.f : 0.f;

    // ---- U = S·P ; G = P·U ; H = S·G ----
    f32x16 U = matmul(FS, FP, Z0);
    Frag8 BU; bconv(U, h, 1.f, BU);
    f32x16 G = matmul(FP, BU, Z0);
    Frag8 BG; bconv(G, h, 1.f, BG);
    f32x16 H = matmul(FS, BG, Z0);

    // ---- M = 2DT·U − 2DT²·H  (D-layout f32) ----
    f32x16 M;
#pragma unroll
    for (int i = 0; i < 16; ++i) M[i] = 0.02f * U[i] - 2e-4f * H[i];

    // A-fragment of M^T == B-fragment of M (cheap lane-pair exchange)
    Frag8 FM; bconv(M, h, 1.f, FM);

    // ---- E = exp(M^T) by Horner Taylor-7: X = I + (1/d)·M^T·X, d=7..1 ----
    f32x16 X = If;
#pragma unroll
    for (int d = 7; d >= 1; --d) {
        Frag8 BX; bconv(X, h, 1.f / (float)d, BX);
        X = matmul(FM, BX, If);
    }

    // ---- Y = S·E with hi/lo split (Shi·Ehi + Slo·Ehi + Shi·Elo) ----
    Frag8 BE, BEl;
    bconv_split(X, h, BE, BEl);
    Frag8 FSl;
    {
        const uint4 c0 = *(const uint4*)(sl + fr * NPAD + h * 8);
        const uint4 c1 = *(const uint4*)(sl + fr * NPAD + 16 + h * 8);
        FSl.r[0]=c0.x; FSl.r[1]=c0.y; FSl.r[2]=c0.z; FSl.r[3]=c0.w;
        FSl.r[4]=c1.x; FSl.r[5]=c1.y; FSl.r[6]=c1.z; FSl.r[7]=c1.w;
    }
    f32x16 Y = matmul(FS, BE, Z0);
    Y = matmul(FSl, BE, Y);
    Y = matmul(FS, BEl, Y);

    // ---- sym + eps·I via LDS bounce (intra-wave, in-order DS pipe) ----
#pragma unroll
    for (int i = 0; i < 16; ++i) {
        const int r = (i & 3) + 8 * (i >> 2) + 4 * h;
        sy[r * FPAD + fr] = Y[i];
    }
    const size_t obase = (size_t)bn * 1027;
#pragma unroll
    for (int k = 0; k < 16; ++k) {
        const int idx = k * 64 + l;
        const int r = idx >> 5, c = idx & 31;
        const float a = sy[r * FPAD + c];
        const float b = sy[c * FPAD + r];
        float v = 0.5f * (a + b);
        if (r == c) v += 1e-8f;
        out[obase + idx] = v;
    }
}

__global__ __launch_bounds__(256)
void leapfrog_phi(const float* __restrict__ phi, const float* __restrict__ piphi,
                  float* __restrict__ out, int total)
{
    const int i = blockIdx.x * blockDim.x + threadIdx.x;
    if (i >= total) return;
    const double TWO_PI = 6.283185307179586476925287;
    const double PI_    = 3.141592653589793238462643;
    const double x = (double)phi[3 * i + 0] + 0.01 * (double)piphi[3 * i + 0];
    const double y = (double)phi[3 * i + 1] + 0.01 * (double)piphi[3 * i + 1];
    const double z = (double)phi[3 * i + 2] + 0.01 * (double)piphi[3 * i + 2];
    const double theta = sqrt(x * x + y * y + z * z);
    const double ts = theta > 1e-12 ? theta : 1e-12;
    const double ax = x / ts, ay = y / ts, az = z / ts;
    const double tw = fmod(theta, TWO_PI);
    double t, sgn;
    if (tw > PI_) { t = TWO_PI - tw; sgn = -1.0; }
    else          { t = tw;          sgn = 1.0;  }
    const double rmax = PI_ - 0.01;
    if (t > rmax) t = rmax;
    const double f = sgn * t;
    const size_t base = (size_t)i * 1027 + 1024;
    out[base + 0] = (float)(ax * f);
    out[base + 1] = (float)(ay * f);
    out[base + 2] = (float)(az * f);
}

extern "C" void kernel_launch(void* const* d_in, const int* in_sizes, int n_in,
                              void* d_out, int out_size, void* d_ws, size_t ws_size,
                              hipStream_t stream)
{
    const float* Sg     = (const float*)d_in[0];
    const float* Pg     = (const float*)d_in[1];
    const float* phig   = (const float*)d_in[2];
    const float* piphig = (const float*)d_in[3];
    float* out = (float*)d_out;

    const int total = in_sizes[0] / 1024;   // B*N = 32768 matrices

    leapfrog_mat<<<(total + 3) / 4, 256, 0, stream>>>(Sg, Pg, out, total);
    leapfrog_phi<<<(total + 255) / 256, 256, 0, stream>>>(phig, piphig, out, total);
}

// Round 4
// 95.420 us; speedup vs baseline: 15.2200x; 1.0089x over previous
//
#include <hip/hip_runtime.h>
#include <hip/hip_bf16.h>
#include <math.h>

// Leapfrog on SPD(32), eigh-free, inverse-free, barrier-free MFMA version.
//   U = S·P ; G = P·U (= PSP) ; pi_half = P - DT·G
//   M = 2DT·S·pi_half = 0.02·U - 2e-4·H,  H = S·G
//   Sigma_new = sym(exp(M)·S) + 1e-8·I = sym(S·exp(M^T)) + 1e-8·I
// One wave per matrix; 32x32x16 bf16 MFMA; fragments loaded DIRECTLY from
// global (A-frag of a row-major matrix = 2x8 contiguous f32 per lane) and
// converted in-register. D-layout results -> B-fragments via lane-pair
// (c, c+32) __shfl_xor exchange. ||M||<~0.15 -> Taylor-5, no squaring.
// Final S·E in hi/lo split bf16. phi retraction fused (lane 0, double).

typedef unsigned int u32;
typedef __attribute__((ext_vector_type(8))) short bf16x8;
typedef __attribute__((ext_vector_type(16))) float f32x16;

#define FPAD 33   // f32 row stride of sym buffer: 33 mod 32 == 1 -> conflict-free

union U4 { u32 u[4]; bf16x8 v; };

__device__ __forceinline__ bf16x8 mk8(u32 a, u32 b, u32 c, u32 d) {
    U4 t; t.u[0] = a; t.u[1] = b; t.u[2] = c; t.u[3] = d; return t.v;
}

__device__ __forceinline__ u32 pk2(float x, float y) {
    float2 f2; f2.x = x; f2.y = y;
    __hip_bfloat162 h2 = __float22bfloat162_rn(f2);
    union { __hip_bfloat162 h; u32 u; } c; c.h = h2; return c.u;
}

__device__ __forceinline__ float asfloat(u32 b) {
    union { u32 u; float f; } c; c.u = b; return c.f;
}

struct Frag8 { u32 r[8]; };

// exchange packed-pair regs p[8] (D-layout pairs) into B-fragment order
__device__ __forceinline__ void xchg(const u32* p, int h, Frag8& B) {
    u32 s0 = h ? p[0] : p[2];
    u32 s1 = h ? p[1] : p[3];
    u32 r0 = __shfl_xor(s0, 32, 64);
    u32 r1 = __shfl_xor(s1, 32, 64);
    B.r[0] = h ? r0 : p[0];
    B.r[1] = h ? r1 : p[1];
    B.r[2] = h ? p[2] : r0;
    B.r[3] = h ? p[3] : r1;
    u32 s2 = h ? p[4] : p[6];
    u32 s3 = h ? p[5] : p[7];
    u32 r2 = __shfl_xor(s2, 32, 64);
    u32 r3 = __shfl_xor(s3, 32, 64);
    B.r[4] = h ? r2 : p[4];
    B.r[5] = h ? r3 : p[5];
    B.r[6] = h ? p[6] : r2;
    B.r[7] = h ? p[7] : r3;
}

// D-layout f32x16 -> bf16 B-fragment (optionally pre-scaled)
__device__ __forceinline__ void bconv(const f32x16& X, int h, float scale, Frag8& B) {
    u32 p[8];
#pragma unroll
    for (int i = 0; i < 8; ++i) p[i] = pk2(X[2*i] * scale, X[2*i+1] * scale);
    xchg(p, h, B);
}

// D-layout f32x16 -> hi and lo bf16 B-fragments (error-compensated split)
__device__ __forceinline__ void bconv_split(const f32x16& X, int h, Frag8& Bh, Frag8& Bl) {
    u32 p[8], q[8];
#pragma unroll
    for (int i = 0; i < 8; ++i) {
        p[i] = pk2(X[2*i], X[2*i+1]);
        const float hx = asfloat(p[i] << 16);
        const float hy = asfloat(p[i] & 0xffff0000u);
        q[i] = pk2(X[2*i] - hx, X[2*i+1] - hy);
    }
    xchg(p, h, Bh);
    xchg(q, h, Bl);
}

__device__ __forceinline__ f32x16 MFMA1(const u32* a, const u32* b, f32x16 acc) {
    return __builtin_amdgcn_mfma_f32_32x32x16_bf16(
        mk8(a[0], a[1], a[2], a[3]), mk8(b[0], b[1], b[2], b[3]), acc, 0, 0, 0);
}

__device__ __forceinline__ f32x16 matmul(const Frag8& A, const Frag8& B, f32x16 acc) {
    acc = MFMA1(A.r,     B.r,     acc);   // k = 0..15
    acc = MFMA1(A.r + 4, B.r + 4, acc);   // k = 16..31
    return acc;
}

__global__ __launch_bounds__(256)
void leapfrog_fused(const float* __restrict__ Sg, const float* __restrict__ Pg,
                    const float* __restrict__ phig, const float* __restrict__ piphig,
                    float* __restrict__ out, int total)
{
    __shared__ __align__(16) float symb[4 * 32 * FPAD];

    const int w  = threadIdx.x >> 6;
    const int l  = threadIdx.x & 63;
    const int bn = blockIdx.x * 4 + w;
    if (bn >= total) return;            // wave-uniform; kernel has no barriers

    float* sy = symb + w * 32 * FPAD;

    const int fr = l & 31;
    const int h  = l >> 5;
    const size_t gbase = (size_t)bn * 1024;

    // ---- fragment loads straight from global: rows of S and P ----
    const float* Srow = Sg + gbase + fr * 32 + h * 8;
    const float* Prow = Pg + gbase + fr * 32 + h * 8;
    const float4 s0 = *(const float4*)(Srow +  0);
    const float4 s1 = *(const float4*)(Srow +  4);
    const float4 s2 = *(const float4*)(Srow + 16);
    const float4 s3 = *(const float4*)(Srow + 20);
    const float4 p0 = *(const float4*)(Prow +  0);
    const float4 p1 = *(const float4*)(Prow +  4);
    const float4 p2 = *(const float4*)(Prow + 16);
    const float4 p3 = *(const float4*)(Prow + 20);

    Frag8 FS, FSl, FP;
    {
        const float4 sv[4] = {s0, s1, s2, s3};
#pragma unroll
        for (int i = 0; i < 4; ++i) {
            const u32 ha = pk2(sv[i].x, sv[i].y);
            const u32 hb = pk2(sv[i].z, sv[i].w);
            FS.r[2*i]   = ha;
            FS.r[2*i+1] = hb;
            FSl.r[2*i]   = pk2(sv[i].x - asfloat(ha << 16), sv[i].y - asfloat(ha & 0xffff0000u));
            FSl.r[2*i+1] = pk2(sv[i].z - asfloat(hb << 16), sv[i].w - asfloat(hb & 0xffff0000u));
        }
        const float4 pv[4] = {p0, p1, p2, p3};
#pragma unroll
        for (int i = 0; i < 4; ++i) {
            FP.r[2*i]   = pk2(pv[i].x, pv[i].y);
            FP.r[2*i+1] = pk2(pv[i].z, pv[i].w);
        }
    }

    f32x16 Z0;
#pragma unroll
    for (int i = 0; i < 16; ++i) Z0[i] = 0.f;

    // identity in D-layout: row (i&3)+8*(i>>2)+4h, col fr
    f32x16 If;
#pragma unroll
    for (int i = 0; i < 16; ++i)
        If[i] = (((i & 3) + 8 * (i >> 2) + 4 * h) == fr) ? 1.f : 0.f;

    // ---- U = S·P ; G = P·U ; H = S·G ----
    f32x16 U = matmul(FS, FP, Z0);
    Frag8 BU; bconv(U, h, 1.f, BU);
    f32x16 G = matmul(FP, BU, Z0);
    Frag8 BG; bconv(G, h, 1.f, BG);
    f32x16 H = matmul(FS, BG, Z0);

    // ---- M = 2DT·U − 2DT²·H  (D-layout f32) ----
    f32x16 M;
#pragma unroll
    for (int i = 0; i < 16; ++i) M[i] = 0.02f * U[i] - 2e-4f * H[i];

    // A-fragment of M^T == B-fragment of M (cheap lane-pair exchange)
    Frag8 FM; bconv(M, h, 1.f, FM);

    // ---- E = exp(M^T) by Horner Taylor-5: X = I + (1/d)·M^T·X, d=5..1 ----
    f32x16 X = If;
#pragma unroll
    for (int d = 5; d >= 1; --d) {
        Frag8 BX; bconv(X, h, 1.f / (float)d, BX);
        X = matmul(FM, BX, If);
    }

    // ---- Y^T = S·E with hi/lo split (Shi·Ehi + Slo·Ehi + Shi·Elo) ----
    Frag8 BE, BEl;
    bconv_split(X, h, BE, BEl);
    f32x16 Y = matmul(FS, BE, Z0);
    Y = matmul(FSl, BE, Y);
    Y = matmul(FS, BEl, Y);

    // ---- sym + eps·I via conflict-free LDS bounce (intra-wave ordering) ----
#pragma unroll
    for (int i = 0; i < 16; ++i) {
        const int r = (i & 3) + 8 * (i >> 2) + 4 * h;
        sy[r * FPAD + fr] = Y[i];
    }
    const size_t obase = (size_t)bn * 1027;
#pragma unroll
    for (int k = 0; k < 16; ++k) {
        const int idx = k * 64 + l;
        const int r = idx >> 5, c = idx & 31;
        const float a = sy[r * FPAD + c];
        const float b = sy[c * FPAD + r];
        float v = 0.5f * (a + b);
        if (r == c) v += 1e-8f;
        out[obase + idx] = v;
    }

    // ---- fused phi retraction (lane 0, double to match f64 branch choices) ----
    if (l == 0) {
        const double TWO_PI = 6.283185307179586476925287;
        const double PI_    = 3.141592653589793238462643;
        const double x = (double)phig[3 * bn + 0] + 0.01 * (double)piphig[3 * bn + 0];
        const double y = (double)phig[3 * bn + 1] + 0.01 * (double)piphig[3 * bn + 1];
        const double z = (double)phig[3 * bn + 2] + 0.01 * (double)piphig[3 * bn + 2];
        const double theta = sqrt(x * x + y * y + z * z);
        const double ts = theta > 1e-12 ? theta : 1e-12;
        const double tw = fmod(theta, TWO_PI);
        double t, sgn;
        if (tw > PI_) { t = TWO_PI - tw; sgn = -1.0; }
        else          { t = tw;          sgn = 1.0;  }
        const double rmax = PI_ - 0.01;
        if (t > rmax) t = rmax;
        const double f = sgn * t / ts;
        out[obase + 1024] = (float)(x * f);
        out[obase + 1025] = (float)(y * f);
        out[obase + 1026] = (float)(z * f);
    }
}

extern "C" void kernel_launch(void* const* d_in, const int* in_sizes, int n_in,
                              void* d_out, int out_size, void* d_ws, size_t ws_size,
                              hipStream_t stream)
{
    const float* Sg     = (const float*)d_in[0];
    const float* Pg     = (const float*)d_in[1];
    const float* phig   = (const float*)d_in[2];
    const float* piphig = (const float*)d_in[3];
    float* out = (float*)d_out;

    const int total = in_sizes[0] / 1024;   // B*N = 32768 matrices

    leapfrog_fused<<<(total + 3) / 4, 256, 0, stream>>>(Sg, Pg, phig, piphig, out, total);
}

// Round 6
// 70.058 us; speedup vs baseline: 20.7299x; 1.3620x over previous
//
#include <hip/hip_runtime.h>
#include <hip/hip_bf16.h>
#include <math.h>

// Leapfrog on SPD(32), eigh-free, inverse-free, barrier-free MFMA version.
//   U = S·P ; G = P·U (= PSP, sym) ; pi_half = P - DT·G
//   M = 2DT·S·pi_half = 0.02·U - 2e-4·H,  H = S·G
//   Sigma_new = sym(exp(M)·S) + 1e-8·I = sym(S·exp(M^T)) + 1e-8·I
// One wave per matrix; 32x32x16 bf16 MFMA; fragments straight from global,
// converted with single-op v_perm_b32 truncation packs; D-layout -> B-frag
// via v_permlane32_swap_b32. TRUE HW semantics (verified by R5 failure +
// ISA doc): swap32(x,y) exchanges x.lanes[32:63] <-> y.lanes[0:31]; so the
// pair (x=p[lo], y=p[hi]) yields B.r[lo]=x, B.r[hi]=y directly.
// ||M||<~0.16 -> Taylor-4. Final S·E in exact hi/lo split bf16.
// phi retraction fused (lane 0, double, floor-based mod-2pi).

typedef unsigned int u32;
typedef __attribute__((ext_vector_type(8))) short bf16x8;
typedef __attribute__((ext_vector_type(16))) float f32x16;

#define FPAD 33   // f32 row stride of sym buffer: 33 mod 32 == 1 -> conflict-free

union U4 { u32 u[4]; bf16x8 v; };

__device__ __forceinline__ bf16x8 mk8(u32 a, u32 b, u32 c, u32 d) {
    U4 t; t.u[0] = a; t.u[1] = b; t.u[2] = c; t.u[3] = d; return t.v;
}

// pack bf16(x),bf16(y) (truncated) into one u32: low16 = x, high16 = y
__device__ __forceinline__ u32 pkt(float x, float y) {
    return __builtin_amdgcn_perm(__float_as_uint(y), __float_as_uint(x), 0x07060302u);
}

struct Frag8 { u32 r[8]; };

// v_permlane32_swap_b32: x.lanes[32:63] <-> y.lanes[0:31]
__device__ __forceinline__ void swap32(u32& x, u32& y) {
    asm("v_permlane32_swap_b32 %0, %1" : "+v"(x), "+v"(y));
}

// packed-pair regs p[8] (D-layout pairs) -> B-fragment order.
// Want: B.r[lo] = {lanes 0-31: own p[lo]; lanes 32-63: partner's p[hi]}
//       B.r[hi] = {lanes 0-31: partner's p[lo]... wait, partner's p[lo] is what
//                  lanes 32-63 hold after their swap} — precisely:
//       B.r[hi] = {lanes 0-31: p[lo] from lane l+32? no: see derivation}
// Derivation: swap32(x=p[lo], y=p[hi]):
//   x.lanes[32:63] <- old y.lanes[0:31]  = p[hi] of lane l-32   -> x == B.r[lo]
//   y.lanes[0:31]  <- old x.lanes[32:63] = p[lo] of lane l+32   -> y == B.r[hi]
__device__ __forceinline__ void xchg(const u32* p, Frag8& B) {
    { u32 x = p[0], y = p[2]; swap32(x, y); B.r[0] = x; B.r[2] = y; }
    { u32 x = p[1], y = p[3]; swap32(x, y); B.r[1] = x; B.r[3] = y; }
    { u32 x = p[4], y = p[6]; swap32(x, y); B.r[4] = x; B.r[6] = y; }
    { u32 x = p[5], y = p[7]; swap32(x, y); B.r[5] = x; B.r[7] = y; }
}

// D-layout f32x16 -> bf16 B-fragment (optionally pre-scaled), trunc pack
__device__ __forceinline__ void bconv(const f32x16& X, float scale, Frag8& B) {
    u32 p[8];
#pragma unroll
    for (int i = 0; i < 8; ++i) p[i] = pkt(X[2*i] * scale, X[2*i+1] * scale);
    xchg(p, B);
}

// D-layout f32x16 -> exact hi/lo split bf16 B-fragments
__device__ __forceinline__ void bconv_split(const f32x16& X, Frag8& Bh, Frag8& Bl) {
    u32 p[8], q[8];
#pragma unroll
    for (int i = 0; i < 8; ++i) {
        const float x = X[2*i], y = X[2*i+1];
        p[i] = pkt(x, y);
        const float lx = x - __uint_as_float(__float_as_uint(x) & 0xffff0000u);
        const float ly = y - __uint_as_float(__float_as_uint(y) & 0xffff0000u);
        q[i] = pkt(lx, ly);
    }
    xchg(p, Bh);
    xchg(q, Bl);
}

__device__ __forceinline__ f32x16 MFMA1(const u32* a, const u32* b, f32x16 acc) {
    return __builtin_amdgcn_mfma_f32_32x32x16_bf16(
        mk8(a[0], a[1], a[2], a[3]), mk8(b[0], b[1], b[2], b[3]), acc, 0, 0, 0);
}

__device__ __forceinline__ f32x16 matmul(const Frag8& A, const Frag8& B, f32x16 acc) {
    acc = MFMA1(A.r,     B.r,     acc);   // k = 0..15
    acc = MFMA1(A.r + 4, B.r + 4, acc);   // k = 16..31
    return acc;
}

__global__ __launch_bounds__(256)
void leapfrog_fused(const float* __restrict__ Sg, const float* __restrict__ Pg,
                    const float* __restrict__ phig, const float* __restrict__ piphig,
                    float* __restrict__ out, int total)
{
    __shared__ __align__(16) float symb[4 * 32 * FPAD];

    const int w  = threadIdx.x >> 6;
    const int l  = threadIdx.x & 63;
    const int bn = blockIdx.x * 4 + w;
    if (bn >= total) return;            // wave-uniform; kernel has no barriers

    float* sy = symb + w * 32 * FPAD;

    const int fr = l & 31;
    const int h  = l >> 5;
    const size_t gbase = (size_t)bn * 1024;

    // ---- fragment loads straight from global: rows of S and P ----
    const float* Srow = Sg + gbase + fr * 32 + h * 8;
    const float* Prow = Pg + gbase + fr * 32 + h * 8;
    const float4 sv[4] = { *(const float4*)(Srow +  0), *(const float4*)(Srow +  4),
                           *(const float4*)(Srow + 16), *(const float4*)(Srow + 20) };
    const float4 pv[4] = { *(const float4*)(Prow +  0), *(const float4*)(Prow +  4),
                           *(const float4*)(Prow + 16), *(const float4*)(Prow + 20) };

    Frag8 FS, FSl, FP;
#pragma unroll
    for (int i = 0; i < 4; ++i) {
        FS.r[2*i]   = pkt(sv[i].x, sv[i].y);
        FS.r[2*i+1] = pkt(sv[i].z, sv[i].w);
        const float lx = sv[i].x - __uint_as_float(__float_as_uint(sv[i].x) & 0xffff0000u);
        const float ly = sv[i].y - __uint_as_float(__float_as_uint(sv[i].y) & 0xffff0000u);
        const float lz = sv[i].z - __uint_as_float(__float_as_uint(sv[i].z) & 0xffff0000u);
        const float lw = sv[i].w - __uint_as_float(__float_as_uint(sv[i].w) & 0xffff0000u);
        FSl.r[2*i]   = pkt(lx, ly);
        FSl.r[2*i+1] = pkt(lz, lw);
        FP.r[2*i]   = pkt(pv[i].x, pv[i].y);
        FP.r[2*i+1] = pkt(pv[i].z, pv[i].w);
    }

    f32x16 Z0;
#pragma unroll
    for (int i = 0; i < 16; ++i) Z0[i] = 0.f;

    // identity in D-layout: row (i&3)+8*(i>>2)+4h, col fr
    f32x16 If;
#pragma unroll
    for (int i = 0; i < 16; ++i)
        If[i] = (((i & 3) + 8 * (i >> 2) + 4 * h) == fr) ? 1.f : 0.f;

    // ---- U = S·P ; G = P·U ; H = S·G ----
    f32x16 U = matmul(FS, FP, Z0);
    Frag8 BU; bconv(U, 1.f, BU);
    f32x16 G = matmul(FP, BU, Z0);
    Frag8 BG; bconv(G, 1.f, BG);
    f32x16 H = matmul(FS, BG, Z0);

    // ---- M = 2DT·U − 2DT²·H  (D-layout f32) ----
    f32x16 M;
#pragma unroll
    for (int i = 0; i < 16; ++i) M[i] = 0.02f * U[i] - 2e-4f * H[i];

    // A-fragment of M^T == B-fragment of M (lane-pair exchange)
    Frag8 FM; bconv(M, 1.f, FM);

    // ---- E = exp(M^T) by Horner Taylor-4: X = I + (1/d)·M^T·X, d=4..1 ----
    f32x16 X = If;
#pragma unroll
    for (int d = 4; d >= 1; --d) {
        Frag8 BX; bconv(X, 1.f / (float)d, BX);
        X = matmul(FM, BX, If);
    }

    // ---- Y^T = S·E, hi/lo split, two independent accumulator chains ----
    Frag8 BE, BEl;
    bconv_split(X, BE, BEl);
    f32x16 Y1 = matmul(FS, BE, Z0);
    f32x16 Y2 = matmul(FSl, BE, Z0);
    Y2 = matmul(FS, BEl, Y2);

    // ---- sym + eps·I via conflict-free LDS bounce (intra-wave ordering) ----
#pragma unroll
    for (int i = 0; i < 16; ++i) {
        const int r = (i & 3) + 8 * (i >> 2) + 4 * h;
        sy[r * FPAD + fr] = Y1[i] + Y2[i];
    }
    const size_t obase = (size_t)bn * 1027;
#pragma unroll
    for (int k = 0; k < 16; ++k) {
        const int idx = k * 64 + l;
        const int r = idx >> 5, c = idx & 31;
        const float a = sy[r * FPAD + c];
        const float b = sy[c * FPAD + r];
        float v = 0.5f * (a + b);
        if (r == c) v += 1e-8f;
        __builtin_nontemporal_store(v, &out[obase + idx]);
    }

    // ---- fused phi retraction (lane 0, double; floor-based mod 2pi) ----
    if (l == 0) {
        const double TWO_PI = 6.283185307179586476925287;
        const double PI_    = 3.141592653589793238462643;
        const double x = (double)phig[3 * bn + 0] + 0.01 * (double)piphig[3 * bn + 0];
        const double y = (double)phig[3 * bn + 1] + 0.01 * (double)piphig[3 * bn + 1];
        const double z = (double)phig[3 * bn + 2] + 0.01 * (double)piphig[3 * bn + 2];
        const double theta = sqrt(x * x + y * y + z * z);
        const double ts = theta > 1e-12 ? theta : 1e-12;
        const double k2 = floor(theta * (1.0 / TWO_PI));
        const double tw = theta - k2 * TWO_PI;          // == fmod(theta, 2pi) for theta>=0
        double t, sgn;
        if (tw > PI_) { t = TWO_PI - tw; sgn = -1.0; }
        else          { t = tw;          sgn = 1.0;  }
        const double rmax = PI_ - 0.01;
        if (t > rmax) t = rmax;
        const double f = sgn * t / ts;
        __builtin_nontemporal_store((float)(x * f), &out[obase + 1024]);
        __builtin_nontemporal_store((float)(y * f), &out[obase + 1025]);
        __builtin_nontemporal_store((float)(z * f), &out[obase + 1026]);
    }
}

extern "C" void kernel_launch(void* const* d_in, const int* in_sizes, int n_in,
                              void* d_out, int out_size, void* d_ws, size_t ws_size,
                              hipStream_t stream)
{
    const float* Sg     = (const float*)d_in[0];
    const float* Pg     = (const float*)d_in[1];
    const float* phig   = (const float*)d_in[2];
    const float* piphig = (const float*)d_in[3];
    float* out = (float*)d_out;

    const int total = in_sizes[0] / 1024;   // B*N = 32768 matrices

    leapfrog_fused<<<(total + 3) / 4, 256, 0, stream>>>(Sg, Pg, phig, piphig, out, total);
}